// Round 1
// baseline (3298.096 us; speedup 1.0000x reference)
//
#include <hip/hip_runtime.h>
#include <stdint.h>

#define TT 2048
#define BB 128
#define DD 100
#define HH 100
#define GG 300   // 3*H, PyTorch gate order [r,z,n]
#define NT 31
#define NEGV (-10000.0f)

// ---------------------------------------------------------------------------
// Kernel 1: gi[dir][t][g] = x_dir(t) @ w_ih^T + b_ih  for the selected batch
// row only (seq).  dir 1 consumes the time-reversed sentence.
// ---------------------------------------------------------------------------
__global__ __launch_bounds__(320) void gi_kernel(
    const float* __restrict__ sent, const int* __restrict__ seqp,
    const float* __restrict__ w_ih_f, const float* __restrict__ b_ih_f,
    const float* __restrict__ w_ih_b, const float* __restrict__ b_ih_b,
    float* __restrict__ gi)
{
    const int t   = blockIdx.x;
    const int dir = blockIdx.y;
    const int j   = threadIdx.x;
    const int seq = seqp[0];
    const int ts  = dir ? (TT - 1 - t) : t;
    __shared__ __align__(16) float x_s[DD];
    if (j < DD) x_s[j] = sent[((size_t)ts * BB + seq) * DD + j];
    __syncthreads();
    if (j < GG) {
        const float* w = dir ? w_ih_b : w_ih_f;
        const float* b = dir ? b_ih_b : b_ih_f;
        const float4* w4 = (const float4*)(w + j * DD);   // j*400B: 16B aligned
        const float4* x4 = (const float4*)x_s;
        float a0 = 0.f, a1 = 0.f, a2 = 0.f, a3 = 0.f;
        #pragma unroll
        for (int k = 0; k < DD / 4; k++) {
            float4 wv = w4[k], xv = x4[k];
            a0 += wv.x * xv.x; a1 += wv.y * xv.y;
            a2 += wv.z * xv.z; a3 += wv.w * xv.w;
        }
        gi[((size_t)dir * TT + t) * GG + j] = b[j] + (a0 + a1) + (a2 + a3);
    }
}

// ---------------------------------------------------------------------------
// Kernel 2: the sequential GRU recurrence.  One block per direction.
// Thread j < 300 owns row j of W_hh in VGPRs; h lives in LDS (broadcast).
// hbuf is stored in forward-time order for both directions.
// ---------------------------------------------------------------------------
__global__ __launch_bounds__(320) void gru_seq_kernel(
    const float* __restrict__ gi,
    const float* __restrict__ w_hh_f, const float* __restrict__ b_hh_f,
    const float* __restrict__ w_hh_b, const float* __restrict__ b_hh_b,
    float* __restrict__ hbuf)
{
    const int dir = blockIdx.x;
    const int j   = threadIdx.x;
    const float* w_hh = dir ? w_hh_b : w_hh_f;
    const float* b_hh = dir ? b_hh_b : b_hh_f;
    const float* gid  = gi   + (size_t)dir * TT * GG;
    float*       hb   = hbuf + (size_t)dir * TT * HH;

    __shared__ __align__(16) float h_s[HH];
    __shared__ float s_rz[2 * HH];   // gi+gh combined for r,z
    __shared__ float s_hn[HH];       // gh_n (kept separate: n = tanh(gi_n + r*gh_n))
    __shared__ float s_gn[HH];       // gi_n

    float4 wreg[DD / 4];
    float  bj = 0.f;
    if (j < GG) {
        const float4* w4 = (const float4*)(w_hh + j * DD);
        #pragma unroll
        for (int k = 0; k < DD / 4; k++) wreg[k] = w4[k];
        bj = b_hh[j];
    }
    if (j < HH) h_s[j] = 0.f;
    __syncthreads();

    for (int t = 0; t < TT; t++) {
        if (j < GG) {
            float gv = gid[t * GG + j];         // independent of h: hidden by FMAs
            float a0 = bj, a1 = 0.f, a2 = 0.f, a3 = 0.f;
            const float4* h4 = (const float4*)h_s;
            #pragma unroll
            for (int k = 0; k < DD / 4; k++) {
                float4 hv = h4[k];
                a0 += wreg[k].x * hv.x; a1 += wreg[k].y * hv.y;
                a2 += wreg[k].z * hv.z; a3 += wreg[k].w * hv.w;
            }
            float acc = (a0 + a1) + (a2 + a3);
            if (j < 2 * HH) s_rz[j] = acc + gv;
            else { s_hn[j - 2 * HH] = acc; s_gn[j - 2 * HH] = gv; }
        }
        __syncthreads();
        if (j < HH) {
            float r   = 1.f / (1.f + __expf(-s_rz[j]));
            float z   = 1.f / (1.f + __expf(-s_rz[HH + j]));
            float pre = s_gn[j] + r * s_hn[j];
            pre = fmaxf(fminf(pre, 40.f), -40.f);        // tanh overflow guard
            float e2  = __expf(-2.f * pre);
            float n   = (1.f - e2) / (1.f + e2);
            float hv  = (1.f - z) * n + z * h_s[j];
            h_s[j] = hv;
            int tt2 = dir ? (TT - 1 - t) : t;            // bwd: store reversed
            hb[(size_t)tt2 * HH + j] = hv;
        }
        __syncthreads();
    }
}

// ---------------------------------------------------------------------------
// Kernel 3: feats[t][n] = concat(fwd_h[t], bwd_h[t]) . w_out[n] + b_out[n]
// ---------------------------------------------------------------------------
__global__ __launch_bounds__(64) void feats_kernel(
    const float* __restrict__ hbuf, const float* __restrict__ w_out,
    const float* __restrict__ b_out, float* __restrict__ feats)
{
    const int t = blockIdx.x;
    const int n = threadIdx.x;
    __shared__ __align__(16) float hs[2 * HH];
    for (int k = n; k < HH; k += 64) {
        hs[k]      = hbuf[(size_t)t * HH + k];
        hs[HH + k] = hbuf[((size_t)TT + t) * HH + k];
    }
    __syncthreads();
    if (n < NT) {
        const float4* w4 = (const float4*)(w_out + n * 2 * HH); // n*800B aligned
        const float4* h4 = (const float4*)hs;
        float a0 = 0.f, a1 = 0.f, a2 = 0.f, a3 = 0.f;
        #pragma unroll
        for (int k = 0; k < (2 * HH) / 4; k++) {
            float4 wv = w4[k], hv = h4[k];
            a0 += wv.x * hv.x; a1 += wv.y * hv.y;
            a2 += wv.z * hv.z; a3 += wv.w * hv.w;
        }
        feats[t * NT + n] = b_out[n] + (a0 + a1) + (a2 + a3);
    }
}

// ---------------------------------------------------------------------------
// Kernel 4: Viterbi forward + backtrack.  Single wave; lane = next-tag.
// transitions row per lane in VGPRs, fv in LDS, backpointers u8 in LDS.
// ---------------------------------------------------------------------------
__global__ __launch_bounds__(64) void viterbi_kernel(
    const float* __restrict__ feats, const float* __restrict__ mask,
    const int* __restrict__ seqp, const float* __restrict__ trans,
    float* __restrict__ out)
{
    const int lane = threadIdx.x;
    const int seq  = seqp[0];
    const float* mrow = mask + (size_t)seq * TT;
    __shared__ float   fv_s[NT];
    __shared__ uint8_t bp_s[TT * NT];   // 63488 B, fits static LDS limit

    float tr[NT];
    if (lane < NT) {
        #pragma unroll
        for (int p = 0; p < NT; p++) tr[p] = trans[lane * NT + p];
        fv_s[lane] = (lane == 0) ? 0.f : NEGV;
    }
    __syncthreads();

    float feat_cur = 0.f;
    if (lane < NT) feat_cur = feats[lane];
    float m_cur = mrow[0];

    for (int t = 0; t < TT; t++) {
        // prefetch next step's operands (hides ~200cyc L2 latency)
        float feat_next = 0.f, m_next = 0.f;
        if (t + 1 < TT) {
            if (lane < NT) feat_next = feats[(t + 1) * NT + lane];
            m_next = mrow[t + 1];
        }
        float fvn = 0.f; int bpn = 0;
        if (lane < NT) {
            float best = fv_s[0] + tr[0]; int bi = 0;
            #pragma unroll
            for (int p = 1; p < NT; p++) {
                float s = fv_s[p] + tr[p];
                if (s > best) { best = s; bi = p; }   // strict > == first-max (jnp.argmax)
            }
            bool live = m_cur > 0.f;
            fvn = live ? (best + feat_cur) : fv_s[lane];
            bpn = live ? bi : lane;
        }
        __syncthreads();                    // uniform: reads done before writes
        if (lane < NT) {
            fv_s[lane] = fvn;
            bp_s[t * NT + lane] = (uint8_t)bpn;
        }
        __syncthreads();
        feat_cur = feat_next; m_cur = m_next;
    }

    if (lane == 0) {
        float best = fv_s[0]; int bi = 0;
        for (int p = 1; p < NT; p++)
            if (fv_s[p] > best) { best = fv_s[p]; bi = p; }
        out[0] = best;                       // score
        int tag = bi;
        for (int t = TT - 1; t >= 0; t--) {  // path[T-1]=final; path[t]=bp[t+1][path[t+1]]
            out[1 + t] = (float)tag;
            tag = bp_s[t * NT + tag];
        }
    }
}

// ---------------------------------------------------------------------------
extern "C" void kernel_launch(void* const* d_in, const int* in_sizes, int n_in,
                              void* d_out, int out_size, void* d_ws, size_t ws_size,
                              hipStream_t stream) {
    const float* sent   = (const float*)d_in[0];
    const float* mask   = (const float*)d_in[1];
    const float* w_ih_f = (const float*)d_in[2];
    const float* w_hh_f = (const float*)d_in[3];
    const float* b_ih_f = (const float*)d_in[4];
    const float* b_hh_f = (const float*)d_in[5];
    const float* w_ih_b = (const float*)d_in[6];
    const float* w_hh_b = (const float*)d_in[7];
    const float* b_ih_b = (const float*)d_in[8];
    const float* b_hh_b = (const float*)d_in[9];
    const float* w_out  = (const float*)d_in[10];
    const float* b_out  = (const float*)d_in[11];
    const float* trans  = (const float*)d_in[12];
    const int*   seqp   = (const int*)d_in[14];
    float* out = (float*)d_out;

    // workspace layout (floats): gi[2][T][300] | hbuf[2][T][100] | feats[T][31]
    float* gi    = (float*)d_ws;
    float* hbuf  = gi   + (size_t)2 * TT * GG;
    float* feats = hbuf + (size_t)2 * TT * HH;

    gi_kernel<<<dim3(TT, 2), 320, 0, stream>>>(sent, seqp, w_ih_f, b_ih_f,
                                               w_ih_b, b_ih_b, gi);
    gru_seq_kernel<<<2, 320, 0, stream>>>(gi, w_hh_f, b_hh_f, w_hh_b, b_hh_b, hbuf);
    feats_kernel<<<TT, 64, 0, stream>>>(hbuf, w_out, b_out, feats);
    viterbi_kernel<<<1, 64, 0, stream>>>(feats, mask, seqp, trans, out);
}

// Round 2
// 3232.426 us; speedup vs baseline: 1.0203x; 1.0203x over previous
//
#include <hip/hip_runtime.h>
#include <stdint.h>

#define TT 2048
#define BB 128
#define DD 100
#define HH 100
#define GG 300   // 3*H, PyTorch gate order [r,z,n]
#define NT 31
#define NEGV (-10000.0f)

// ---------------------------------------------------------------------------
// Kernel 1: gi[dir][t][g] = x_dir(t) @ w_ih^T + b_ih  for batch row `seq`.
// ---------------------------------------------------------------------------
__global__ __launch_bounds__(320) void gi_kernel(
    const float* __restrict__ sent, const int* __restrict__ seqp,
    const float* __restrict__ w_ih_f, const float* __restrict__ b_ih_f,
    const float* __restrict__ w_ih_b, const float* __restrict__ b_ih_b,
    float* __restrict__ gi)
{
    const int t   = blockIdx.x;
    const int dir = blockIdx.y;
    const int j   = threadIdx.x;
    const int seq = seqp[0];
    const int ts  = dir ? (TT - 1 - t) : t;
    __shared__ __align__(16) float x_s[DD];
    if (j < DD) x_s[j] = sent[((size_t)ts * BB + seq) * DD + j];
    __syncthreads();
    if (j < GG) {
        const float* w = dir ? w_ih_b : w_ih_f;
        const float* b = dir ? b_ih_b : b_ih_f;
        const float4* w4 = (const float4*)(w + j * DD);
        const float4* x4 = (const float4*)x_s;
        float a0 = 0.f, a1 = 0.f, a2 = 0.f, a3 = 0.f;
        #pragma unroll
        for (int k = 0; k < DD / 4; k++) {
            float4 wv = w4[k], xv = x4[k];
            a0 += wv.x * xv.x; a1 += wv.y * xv.y;
            a2 += wv.z * xv.z; a3 += wv.w * xv.w;
        }
        gi[((size_t)dir * TT + t) * GG + j] = b[j] + (a0 + a1) + (a2 + a3);
    }
}

// ---------------------------------------------------------------------------
// Kernel 2: sequential GRU + fused output-projection partials.
// One block per direction, 384 threads (6 waves):
//   threads 0..299  : gate rows (W_hh row in VGPRs)
//   threads 320..350: pfeat rows n (w_out[n, dir-half] in VGPRs) — computed
//                     one step delayed (h stable during phase 1 via ping-pong),
//                     global stores batched every 8 steps (amortize the
//                     vmcnt(0) barrier drain).
// h NEVER goes to global memory.
// ---------------------------------------------------------------------------
__global__ __launch_bounds__(384) void gru_seq_kernel(
    const float* __restrict__ gi,
    const float* __restrict__ w_hh_f, const float* __restrict__ b_hh_f,
    const float* __restrict__ w_hh_b, const float* __restrict__ b_hh_b,
    const float* __restrict__ w_out,
    float* __restrict__ pfeat)           // [2][TT][NT], time in ORIGINAL order
{
    const int dir = blockIdx.x;
    const int j   = threadIdx.x;
    const float* w_hh = dir ? w_hh_b : w_hh_f;
    const float* b_hh = dir ? b_hh_b : b_hh_f;
    const float* gid  = gi + (size_t)dir * TT * GG;
    float* pf = pfeat + (size_t)dir * TT * NT;

    __shared__ __align__(16) float h_s[2][HH];   // ping-pong
    __shared__ float s_rz[2 * HH];
    __shared__ float s_hn[HH];
    __shared__ float s_gn[HH];

    const bool is_gate = (j < GG);
    const int  n       = j - 320;
    const bool is_pf   = (n >= 0) && (n < NT);

    float4 wreg[DD / 4];
    float  bj = 0.f;
    if (is_gate) {
        const float4* w4 = (const float4*)(w_hh + j * DD);
        #pragma unroll
        for (int k = 0; k < DD / 4; k++) wreg[k] = w4[k];
        bj = b_hh[j];
    } else if (is_pf) {
        const float4* w4 = (const float4*)(w_out + n * (2 * HH) + dir * HH);
        #pragma unroll
        for (int k = 0; k < DD / 4; k++) wreg[k] = w4[k];
    }
    if (j < HH) h_s[0][j] = 0.f;
    __syncthreads();

    float pf_hist[8];
    float gv_next = is_gate ? gid[j] : 0.f;   // software prefetch of gi[t]
    int cur = 0;

    for (int t = 0; t < TT; t++) {
        const float4* h4 = (const float4*)h_s[cur];
        if (is_gate) {
            float gv = gv_next;
            if (t + 1 < TT) gv_next = gid[(t + 1) * GG + j];
            float a0 = bj, a1 = 0.f, a2 = 0.f, a3 = 0.f;
            #pragma unroll
            for (int k = 0; k < DD / 4; k++) {
                float4 hv = h4[k];
                a0 += wreg[k].x * hv.x; a1 += wreg[k].y * hv.y;
                a2 += wreg[k].z * hv.z; a3 += wreg[k].w * hv.w;
            }
            float acc = (a0 + a1) + (a2 + a3);
            if (j < 2 * HH) s_rz[j] = acc + gv;
            else { s_hn[j - 2 * HH] = acc; s_gn[j - 2 * HH] = gv; }
        } else if (is_pf) {
            if (t > 0) {                       // pfeat of h after step t-1
                float a0 = 0.f, a1 = 0.f, a2 = 0.f, a3 = 0.f;
                #pragma unroll
                for (int k = 0; k < DD / 4; k++) {
                    float4 hv = h4[k];
                    a0 += wreg[k].x * hv.x; a1 += wreg[k].y * hv.y;
                    a2 += wreg[k].z * hv.z; a3 += wreg[k].w * hv.w;
                }
                pf_hist[(t - 1) & 7] = (a0 + a1) + (a2 + a3);
            }
            if (t >= 8 && (t & 7) == 0) {      // flush pf[t-8 .. t-1]
                int tb = t - 8;
                #pragma unroll
                for (int i = 0; i < 8; i++) {
                    int ot = dir ? (TT - 1 - (tb + i)) : (tb + i);
                    pf[(size_t)ot * NT + n] = pf_hist[i];
                }
            }
        }
        __syncthreads();
        if (j < HH) {
            float r   = 1.f / (1.f + __expf(-s_rz[j]));
            float z   = 1.f / (1.f + __expf(-s_rz[HH + j]));
            float pre = s_gn[j] + r * s_hn[j];
            pre = fmaxf(fminf(pre, 40.f), -40.f);
            float e2  = __expf(-2.f * pre);
            float nn  = (1.f - e2) / (1.f + e2);
            h_s[cur ^ 1][j] = (1.f - z) * nn + z * h_s[cur][j];
        }
        __syncthreads();
        cur ^= 1;
    }

    // epilogue: pf[TT-1] from final h, then flush last batch of 8
    if (is_pf) {
        const float4* h4 = (const float4*)h_s[cur];
        float a0 = 0.f, a1 = 0.f, a2 = 0.f, a3 = 0.f;
        #pragma unroll
        for (int k = 0; k < DD / 4; k++) {
            float4 hv = h4[k];
            a0 += wreg[k].x * hv.x; a1 += wreg[k].y * hv.y;
            a2 += wreg[k].z * hv.z; a3 += wreg[k].w * hv.w;
        }
        pf_hist[7] = (a0 + a1) + (a2 + a3);
        int tb = TT - 8;
        #pragma unroll
        for (int i = 0; i < 8; i++) {
            int ot = dir ? (TT - 1 - (tb + i)) : (tb + i);
            pf[(size_t)ot * NT + n] = pf_hist[i];
        }
    }
}

// ---------------------------------------------------------------------------
// Kernel 3: Viterbi. Single wave, NO barriers in the main loop.
//  - lane = (half, next-state j): half 0 handles prev p=0..15, half 1 p=16..30
//  - fv lives in registers of lanes 0..30; broadcast via ds_bpermute (__shfl)
//  - exact first-max argmax: max-tree, then min-index over achievers
//  - composed 64-step backpointer maps (1 bpermute/step) => parallel backtrack
// ---------------------------------------------------------------------------
__global__ __launch_bounds__(64) void viterbi_kernel(
    const float* __restrict__ pfeat, const float* __restrict__ mask,
    const int* __restrict__ seqp, const float* __restrict__ trans,
    const float* __restrict__ b_out, float* __restrict__ out)
{
    const int lane = threadIdx.x;
    const int half = lane >> 5;
    const int jj   = lane & 31;
    const float* mrow = mask + (size_t)seqp[0] * TT;
    const float* pff = pfeat;
    const float* pfb = pfeat + (size_t)TT * NT;

    __shared__ uint8_t bp_s[TT * NT];    // 63488 B
    __shared__ uint8_t gchk[32 * 32];    // composed map per 64-step block
    __shared__ uint8_t echk[32];         // entry tag per block

    const bool act = (jj < NT);
    const bool low = (half == 0);

    float tr[16];
    #pragma unroll
    for (int pp = 0; pp < 16; pp++) {
        int p = half * 16 + pp;
        tr[pp] = (act && p < NT) ? trans[jj * NT + p] : -3.0e38f;
    }
    float bo = (act && low) ? b_out[jj] : 0.f;

    float fv = (lane == 0) ? 0.f : NEGV;   // meaningful in lanes 0..30
    int   G  = jj;                          // composed backpointer map

    float f_cur = (act && low) ? (pff[jj] + pfb[jj] + bo) : 0.f;
    float m_cur = mrow[0];
    float ffn = 0.f, fbn = 0.f, mn = 0.f;

    for (int t = 0; t < TT; t++) {
        if (t + 1 < TT) {                   // prefetch, stays in flight (no barrier!)
            if (act && low) { ffn = pff[(t + 1) * NT + jj]; fbn = pfb[(t + 1) * NT + jj]; }
            mn = mrow[t + 1];
        }
        // scores for this lane's 16 prev-states
        float sv[16];
        #pragma unroll
        for (int pp = 0; pp < 16; pp++) {
            int p = half * 16 + pp;
            sv[pp] = __shfl(fv, p) + tr[pp];   // p=31 hits tr=-3e38 sentinel
        }
        // half-max (value), tree
        float rv[16];
        #pragma unroll
        for (int pp = 0; pp < 16; pp++) rv[pp] = sv[pp];
        #pragma unroll
        for (int st = 8; st >= 1; st >>= 1)
            #pragma unroll
            for (int q = 0; q < st; q++) rv[q] = fmaxf(rv[q], rv[q + st]);
        float bhalf = rv[0];
        // half-argmax: min index among achievers (exact first-max)
        int iv[16];
        #pragma unroll
        for (int pp = 0; pp < 16; pp++)
            iv[pp] = (sv[pp] >= bhalf) ? (half * 16 + pp) : 99;
        #pragma unroll
        for (int st = 8; st >= 1; st >>= 1)
            #pragma unroll
            for (int q = 0; q < st; q++) iv[q] = min(iv[q], iv[q + st]);
        int ihalf = iv[0];
        // combine the two halves (symmetric, exact)
        float bO = __shfl_xor(bhalf, 32);
        int   iO = __shfl_xor(ihalf, 32);
        float best = fmaxf(bhalf, bO);
        int c1 = (bhalf >= best) ? ihalf : 99;
        int c2 = (bO    >= best) ? iO    : 99;
        int bi = min(c1, c2);

        bool live = m_cur > 0.f;
        float fvn = live ? (best + f_cur) : fv;
        int   bpn = live ? bi : jj;
        if (!(act && low)) { fvn = NEGV; bpn = 0; }
        fv = fvn;
        G = __shfl(G, bpn);                    // compose: G_t[j] = G_{t-1}[bp_t[j]]
        if (act && low) bp_s[t * NT + jj] = (uint8_t)bpn;
        if ((t & 63) == 63) {
            if (act && low) gchk[(t >> 6) * 32 + jj] = (uint8_t)G;
            G = jj;
        }
        f_cur = ffn + fbn + bo;
        m_cur = mn;
    }
    __syncthreads();

    // final argmax over fv[0..30] (uniform readlane loop, every lane computes)
    float fin[32];
    #pragma unroll
    for (int p = 0; p < NT; p++)
        fin[p] = __int_as_float(__builtin_amdgcn_readlane(__float_as_int(fv), p));
    fin[31] = -3.0e38f;
    float mv[32];
    #pragma unroll
    for (int p = 0; p < 32; p++) mv[p] = fin[p];
    #pragma unroll
    for (int st = 16; st >= 1; st >>= 1)
        #pragma unroll
        for (int q = 0; q < st; q++) mv[q] = fmaxf(mv[q], mv[q + st]);
    float fbest = mv[0];
    int ix[32];
    #pragma unroll
    for (int p = 0; p < 32; p++) ix[p] = (fin[p] >= fbest) ? p : 99;
    #pragma unroll
    for (int st = 16; st >= 1; st >>= 1)
        #pragma unroll
        for (int q = 0; q < st; q++) ix[q] = min(ix[q], ix[q + st]);
    int ftag = ix[0];

    if (lane == 0) {
        out[0] = fbest;
        int tag = ftag;                        // tag at t = TT-1 (top of block 31)
        for (int b = 31; b >= 0; b--) { echk[b] = (uint8_t)tag; tag = gchk[b * 32 + tag]; }
    }
    __syncthreads();
    // parallel backtrack: lane b handles 64-step block b
    if (lane < 32) {
        int tag = echk[lane];
        for (int i = 63; i >= 0; i--) {
            int t = lane * 64 + i;
            out[1 + t] = (float)tag;
            tag = bp_s[t * NT + tag];
        }
    }
}

// ---------------------------------------------------------------------------
extern "C" void kernel_launch(void* const* d_in, const int* in_sizes, int n_in,
                              void* d_out, int out_size, void* d_ws, size_t ws_size,
                              hipStream_t stream) {
    const float* sent   = (const float*)d_in[0];
    const float* mask   = (const float*)d_in[1];
    const float* w_ih_f = (const float*)d_in[2];
    const float* w_hh_f = (const float*)d_in[3];
    const float* b_ih_f = (const float*)d_in[4];
    const float* b_hh_f = (const float*)d_in[5];
    const float* w_ih_b = (const float*)d_in[6];
    const float* w_hh_b = (const float*)d_in[7];
    const float* b_ih_b = (const float*)d_in[8];
    const float* b_hh_b = (const float*)d_in[9];
    const float* w_out  = (const float*)d_in[10];
    const float* b_out  = (const float*)d_in[11];
    const float* trans  = (const float*)d_in[12];
    const int*   seqp   = (const int*)d_in[14];
    float* out = (float*)d_out;

    // workspace (floats): gi[2][T][300] | pfeat[2][T][31]
    float* gi    = (float*)d_ws;
    float* pfeat = gi + (size_t)2 * TT * GG;

    gi_kernel<<<dim3(TT, 2), 320, 0, stream>>>(sent, seqp, w_ih_f, b_ih_f,
                                               w_ih_b, b_ih_b, gi);
    gru_seq_kernel<<<2, 384, 0, stream>>>(gi, w_hh_f, b_hh_f, w_hh_b, b_hh_b,
                                          w_out, pfeat);
    viterbi_kernel<<<1, 64, 0, stream>>>(pfeat, mask, seqp, trans, b_out, out);
}